// Round 5
// baseline (2966.188 us; speedup 1.0000x reference)
//
#include <hip/hip_runtime.h>
#include <hip/hip_bf16.h>
#include <math.h>

// Problem constants (reference: N=8192, H=2048, E=8, K=2, CF=1.25)
#define NTOK 8192
#define HDIM 2048
#define NEXP 8
#define TOPK 2
#define CAP  1280            // ceil(1.25 * 8192 / 8)
#define FF   4096            // 2*H

typedef float  f32x4  __attribute__((ext_vector_type(4)));
typedef __bf16 bf16x8 __attribute__((ext_vector_type(8)));

typedef __attribute__((address_space(1))) const unsigned int gas_u32;
typedef __attribute__((address_space(3))) unsigned int las_u32;

__device__ __forceinline__ void gload16(const void* g, void* l) {
    __builtin_amdgcn_global_load_lds((gas_u32*)g, (las_u32*)l, 16, 0, 0);
}
__device__ __forceinline__ void sink(const bf16x8& v) {   // keep a b128 load alive (rule 17)
    const int* p = (const int*)&v;
    asm volatile("" :: "v"(p[0]), "v"(p[1]), "v"(p[2]), "v"(p[3]));
}

__device__ __forceinline__ ushort f2bf(float f) {
    union { float f; unsigned u; } c; c.f = f;
    unsigned u = c.u;
    unsigned r = (u + 0x7FFFu + ((u >> 16) & 1u)) >> 16;   // RNE
    return (ushort)r;
}
__device__ __forceinline__ float bf2f(ushort h) {
    union { unsigned u; float f; } c; c.u = ((unsigned)h) << 16;
    return c.f;
}

// ---------------- tokens f32 -> bf16 ----------------
__global__ void k_convert(const float* __restrict__ src, ushort* __restrict__ dst) {
    int i = (blockIdx.x * 256 + threadIdx.x) * 8;
    float4 a = *(const float4*)(src + i);
    float4 b = *(const float4*)(src + i + 4);
    uint4 o;
    o.x = (unsigned)f2bf(a.x) | ((unsigned)f2bf(a.y) << 16);
    o.y = (unsigned)f2bf(a.z) | ((unsigned)f2bf(a.w) << 16);
    o.z = (unsigned)f2bf(b.x) | ((unsigned)f2bf(b.y) << 16);
    o.w = (unsigned)f2bf(b.z) | ((unsigned)f2bf(b.w) << 16);
    *(uint4*)(dst + i) = o;
}

// ---------------- router: logits (f64 accum), top-2, softmax ----------------
__global__ void k_router(const float* __restrict__ tokens, const float* __restrict__ Wr,
                         const float* __restrict__ br, int* __restrict__ eids,
                         float* __restrict__ probs) {
    int wave = threadIdx.x >> 6, lane = threadIdx.x & 63;
    int t = blockIdx.x * 4 + wave;
    const float* tp = tokens + (size_t)t * HDIM;
    double acc[NEXP];
    #pragma unroll
    for (int e = 0; e < NEXP; ++e) acc[e] = 0.0;
    for (int j = 0; j < HDIM / 64; ++j) {
        float x = tp[j * 64 + lane];
        #pragma unroll
        for (int e = 0; e < NEXP; ++e)
            acc[e] += (double)x * (double)Wr[e * HDIM + j * 64 + lane];
    }
    #pragma unroll
    for (int e = 0; e < NEXP; ++e) {
        #pragma unroll
        for (int off = 32; off; off >>= 1) acc[e] += __shfl_xor(acc[e], off, 64);
    }
    if (lane == 0) {
        float lg[NEXP];
        #pragma unroll
        for (int e = 0; e < NEXP; ++e) lg[e] = (float)acc[e] + br[e];
        int e0 = 0; float s0 = lg[0];
        #pragma unroll
        for (int e = 1; e < NEXP; ++e) if (lg[e] > s0) { s0 = lg[e]; e0 = e; }
        int e1 = -1; float s1 = -1e30f;
        #pragma unroll
        for (int e = 0; e < NEXP; ++e) if (e != e0 && lg[e] > s1) { s1 = lg[e]; e1 = e; }
        float ex = expf(s1 - s0);
        float den = 1.f + ex;
        eids[t * 2] = e0; eids[t * 2 + 1] = e1;
        probs[t * 2] = 1.f / den; probs[t * 2 + 1] = ex / den;
    }
}

// ---------------- deterministic rank/capacity assignment (1 block, 1 wave) ----------------
__global__ void k_assign(const int* __restrict__ eids, int* __restrict__ tok_map,
                         int* __restrict__ dest) {
    __shared__ int cnt[64][NEXP];
    int l = threadIdx.x;
    for (int i = l; i < NEXP * CAP; i += 64) tok_map[i] = 0;
    int c[NEXP];
    #pragma unroll
    for (int e = 0; e < NEXP; ++e) c[e] = 0;
    const int base = l * 256;
    for (int i = 0; i < 256; ++i) {
        int ee = eids[base + i];
        #pragma unroll
        for (int e = 0; e < NEXP; ++e) c[e] += (ee == e);
    }
    #pragma unroll
    for (int e = 0; e < NEXP; ++e) cnt[l][e] = c[e];
    __syncthreads();
    if (l < NEXP) {
        int run = 0;
        for (int b = 0; b < 64; ++b) { int v = cnt[b][l]; cnt[b][l] = run; run += v; }
    }
    __syncthreads();
    int off[NEXP];
    #pragma unroll
    for (int e = 0; e < NEXP; ++e) off[e] = cnt[l][e];
    for (int i = 0; i < 256; ++i) {
        int d = base + i;
        int ee = eids[d];
        int r = -1;
        #pragma unroll
        for (int e = 0; e < NEXP; ++e) { bool m = (ee == e); if (m) r = off[e]; off[e] += m; }
        if (r < CAP) { tok_map[ee * CAP + r] = d >> 1; dest[d] = ee * CAP + r; }
        else dest[d] = -1;
    }
}

// ---------------- W [E][Kd][Nd] f32 -> WT [E][Nd][Kd] bf16, 64x64 tiles ----------------
__global__ __launch_bounds__(256) void k_transpose(const float* __restrict__ src,
                                                   ushort* __restrict__ dst,
                                                   int Kd, int Nd) {
    __shared__ float tl[64][65];
    int e = blockIdx.z;
    int k0 = blockIdx.x * 64, n0 = blockIdx.y * 64;
    const float* s = src + (size_t)e * Kd * Nd;
    ushort* d = dst + (size_t)e * Kd * Nd;
    int tid = threadIdx.x;
    #pragma unroll
    for (int i = 0; i < 4; ++i) {
        int flat = (i * 256 + tid) * 4;
        int kk = flat >> 6, nn = flat & 63;
        float4 v = *(const float4*)(s + (size_t)(k0 + kk) * Nd + n0 + nn);
        tl[kk][nn] = v.x; tl[kk][nn + 1] = v.y; tl[kk][nn + 2] = v.z; tl[kk][nn + 3] = v.w;
    }
    __syncthreads();
    #pragma unroll
    for (int g = 0; g < 4; ++g) {
        int flat = g * 1024 + tid * 4;
        int nn = flat >> 6, kk = flat & 63;
        uint2 o;
        o.x = (unsigned)f2bf(tl[kk][nn])     | ((unsigned)f2bf(tl[kk + 1][nn]) << 16);
        o.y = (unsigned)f2bf(tl[kk + 2][nn]) | ((unsigned)f2bf(tl[kk + 3][nn]) << 16);
        *(uint2*)(d + (size_t)(n0 + nn) * Kd + k0 + kk) = o;
    }
}

// ---------------- grouped bf16 MFMA GEMM, 256x256 8-phase ----------------
// MODE 0 = full (round-4 behavior, known-correct).
// MODE 1 = MFMA+barrier skeleton probe (no staging / no ds_reads; frags from junk LDS).
// MODE 2 = memory skeleton probe (staging + ds_reads + waits; no MFMA; loads sunk).
#define BAR()    __builtin_amdgcn_s_barrier()
#define SCHED0() __builtin_amdgcn_sched_barrier(0)
#define LGKM0()  do { asm volatile("s_waitcnt lgkmcnt(0)" ::: "memory"); SCHED0(); } while (0)
#define VMC4()   do { asm volatile("s_waitcnt vmcnt(4)" ::: "memory"); SCHED0(); } while (0)

template<bool DOGELU, bool GATHER, int MODE>
__global__ __launch_bounds__(512, 2) void k_gemm(const ushort* __restrict__ A,
                                                 const int* __restrict__ tmap,
                                                 const ushort* __restrict__ B,
                                                 const float* __restrict__ bias,
                                                 ushort* __restrict__ C,
                                                 int Kd, int Nd) {
    __shared__ char lds[131072];
    const int tid  = threadIdx.x;
    const int lane = tid & 63;
    const int wave = tid >> 6;
    const int wr = wave >> 2, wc = wave & 3;
    const int e = blockIdx.z;
    const int bm0 = blockIdx.y * 256, bn0 = blockIdx.x * 256;

    const int srow = tid >> 3;
    const int swzc = (tid ^ (tid >> 3)) & 7;
    const ushort* Be = B + (size_t)e * (size_t)Nd * Kd;
    const ushort* pa[4]; const ushort* pb[4];
    #pragma unroll
    for (int h = 0; h < 2; ++h)
        #pragma unroll
        for (int j = 0; j < 2; ++j) {
            int mrow = bm0 + h * 128 + j * 64 + srow;
            int arow = GATHER ? tmap[e * CAP + mrow] : (e * CAP + mrow);
            pa[h * 2 + j] = A  + (size_t)arow * Kd + swzc * 8;
            pb[h * 2 + j] = Be + (size_t)(bn0 + h * 128 + j * 64 + srow) * Kd + swzc * 8;
        }
    const int ldsW = wave * 1024;

    const int fr = lane & 15, kq = lane >> 4;
    const int x0 = ((kq ^ (fr & 7)) * 16);
    const int sA = wr * 16384 + fr * 128;
    const int sB = 65536 + (wc >> 1) * 16384 + ((wc & 1) * 64 + fr) * 128;

    f32x4  acc[8][4] = {};
    bf16x8 bfr[4][2];
    bf16x8 af[4][2];

    if constexpr (MODE == 1) {   // junk-but-live frags; also keeps LDS referenced
        #pragma unroll
        for (int m = 0; m < 4; ++m)
            #pragma unroll
            for (int ks = 0; ks < 2; ++ks) {
                af[m][ks]  = *(const bf16x8*)(lds + ((tid * 16 + (m * 2 + ks) * 1024) & 65535));
                bfr[m][ks] = *(const bf16x8*)(lds + ((tid * 16 + (m * 2 + ks) * 2048 + 512) & 65535));
            }
    }

    auto STAGE_A = [&](int b, int kt) {
        if constexpr (MODE != 1) {
            #pragma unroll
            for (int hj = 0; hj < 4; ++hj)
                gload16(pa[hj] + (size_t)kt * 64,
                        lds + b * 32768 + (hj >> 1) * 16384 + (hj & 1) * 8192 + ldsW);
        }
    };
    auto STAGE_B = [&](int b, int kt) {
        if constexpr (MODE != 1) {
            #pragma unroll
            for (int hj = 0; hj < 4; ++hj)
                gload16(pb[hj] + (size_t)kt * 64,
                        lds + 65536 + b * 32768 + (hj >> 1) * 16384 + (hj & 1) * 8192 + ldsW);
        }
    };
    auto LDA_ = [&](int b, int mh) {
        if constexpr (MODE != 1) {
            #pragma unroll
            for (int m = 0; m < 4; ++m)
                #pragma unroll
                for (int ks = 0; ks < 2; ++ks)
                    af[m][ks] = *(const bf16x8*)(lds + b * 32768 + sA + (mh * 4 + m) * 2048
                                                 + (x0 ^ (ks << 6)));
        }
    };
    auto LDB2 = [&](int b, int nh) {
        if constexpr (MODE != 1) {
            #pragma unroll
            for (int n = 0; n < 2; ++n)
                #pragma unroll
                for (int ks = 0; ks < 2; ++ks)
                    bfr[nh * 2 + n][ks] = *(const bf16x8*)(lds + b * 32768 + sB
                                                           + (nh * 2 + n) * 2048 + (x0 ^ (ks << 6)));
        }
    };
    auto MMA = [&](int mh, int nh) {
        if constexpr (MODE != 2) {
            __builtin_amdgcn_s_setprio(1);
            #pragma unroll
            for (int m = 0; m < 4; ++m)
                #pragma unroll
                for (int n = 0; n < 2; ++n)
                    #pragma unroll
                    for (int ks = 0; ks < 2; ++ks)
                        acc[mh * 4 + m][nh * 2 + n] = __builtin_amdgcn_mfma_f32_16x16x32_bf16(
                            af[m][ks], bfr[nh * 2 + n][ks], acc[mh * 4 + m][nh * 2 + n], 0, 0, 0);
            __builtin_amdgcn_s_setprio(0);
            SCHED0();
        } else {
            #pragma unroll
            for (int m = 0; m < 4; ++m) { sink(af[m][0]); sink(af[m][1]); }
            #pragma unroll
            for (int n = 0; n < 4; ++n) { sink(bfr[n][0]); sink(bfr[n][1]); }
        }
    };

    const int NT  = Kd >> 6;
    const int nt2 = NT >> 1;

    if constexpr (MODE != 1) {
        STAGE_A(0, 0); STAGE_B(0, 0); STAGE_B(1, 1);
        VMC4();
    }
    BAR();

    for (int it = 0; it < nt2; ++it) {
        const int kt1  = 2 * it + 1;
        const int ktN  = min(2 * it + 2, NT - 1);
        const int ktN1 = min(2 * it + 3, NT - 1);
        // ph1
        LDA_(0, 0); LDB2(0, 0);
        STAGE_A(1, kt1);
        BAR(); if constexpr (MODE != 1) LGKM0(); MMA(0, 0); BAR();
        // ph2
        LDB2(0, 1);
        BAR(); if constexpr (MODE != 1) LGKM0(); MMA(0, 1); BAR();
        // ph3
        LDA_(0, 1);
        STAGE_B(0, ktN);
        BAR(); if constexpr (MODE != 1) LGKM0(); MMA(1, 0); BAR();
        // ph4
        if constexpr (MODE != 1) VMC4();
        BAR(); if constexpr (MODE != 1) LGKM0(); MMA(1, 1); BAR();
        // ph5
        LDA_(1, 0); LDB2(1, 0);
        STAGE_A(0, ktN);
        BAR(); if constexpr (MODE != 1) LGKM0(); MMA(0, 0); BAR();
        // ph6
        LDB2(1, 1);
        BAR(); if constexpr (MODE != 1) LGKM0(); MMA(0, 1); BAR();
        // ph7
        LDA_(1, 1);
        STAGE_B(1, ktN1);
        BAR(); if constexpr (MODE != 1) LGKM0(); MMA(1, 0); BAR();
        // ph8
        if constexpr (MODE != 1) VMC4();
        BAR(); if constexpr (MODE != 1) LGKM0(); MMA(1, 1); BAR();
    }

    const float* be = bias + e * Nd;
    ushort* Ce = C + (size_t)e * CAP * Nd;
    const int rl = (lane >> 4) * 4, cl = lane & 15;
    #pragma unroll
    for (int ni = 0; ni < 4; ++ni) {
        int gc = bn0 + wc * 64 + ni * 16 + cl;
        float bv = be[gc];
        #pragma unroll
        for (int mi = 0; mi < 8; ++mi) {
            #pragma unroll
            for (int r = 0; r < 4; ++r) {
                int gr = bm0 + wr * 128 + mi * 16 + rl + r;
                float v = acc[mi][ni][r] + bv;
                if (DOGELU) v = 0.5f * v * (1.f + erff(v * 0.70710678118654752f));
                Ce[(size_t)gr * Nd + gc] = f2bf(v);
            }
        }
    }
}

// ---------------- candidate probe: 256x256, BK=32, 64 KiB LDS -> 2 blocks/CU ----------------
// Simple T3-minimum loop: STAGE(next) -> compute(cur) -> __syncthreads (1 sync/iter).
// Swizzle: LDS k16-chunk pos holds global chunk pos ^ ((row>>1)&3)  (involution both sides).
template<bool DOGELU, bool GATHER>
__global__ __launch_bounds__(512, 4) void k_gemm_bk32(const ushort* __restrict__ A,
                                                      const int* __restrict__ tmap,
                                                      const ushort* __restrict__ B,
                                                      const float* __restrict__ bias,
                                                      ushort* __restrict__ C,
                                                      int Kd, int Nd) {
    __shared__ char lds2[65536];                 // [buf:2][mat:2][256 rows][64 B]
    const int tid = threadIdx.x, lane = tid & 63, wave = tid >> 6;
    const int wr = wave >> 2, wc = wave & 3;
    const int e = blockIdx.z;
    const int bm0 = blockIdx.y * 256, bn0 = blockIdx.x * 256;
    const ushort* Be = B + (size_t)e * (size_t)Nd * Kd;

    // staging: thread handles chunks tid and tid+512 per matrix; row=c>>2
    const int r0 = tid >> 2;
    const int kc = ((tid & 3) ^ ((tid >> 3) & 3)) * 8;   // inverse-swizzled global k-chunk
    int arow0, arow1;
    if (GATHER) { arow0 = tmap[e * CAP + bm0 + r0]; arow1 = tmap[e * CAP + bm0 + r0 + 128]; }
    else        { arow0 = e * CAP + bm0 + r0;       arow1 = e * CAP + bm0 + r0 + 128; }
    const ushort* gA0 = A  + (size_t)arow0 * Kd + kc;
    const ushort* gA1 = A  + (size_t)arow1 * Kd + kc;
    const ushort* gB0 = Be + (size_t)(bn0 + r0) * Kd + kc;
    const ushort* gB1 = Be + (size_t)(bn0 + r0 + 128) * Kd + kc;
    const int ldsW = wave * 1024;

    auto STAGE = [&](int buf, int kt) {
        char* d = lds2 + buf * 32768;
        gload16(gA0 + kt * 32, d + ldsW);
        gload16(gA1 + kt * 32, d + 8192 + ldsW);
        gload16(gB0 + kt * 32, d + 16384 + ldsW);
        gload16(gB1 + kt * 32, d + 24576 + ldsW);
    };

    const int fr = lane & 15, kq = lane >> 4;
    const int x0 = (kq ^ ((fr >> 1) & 3)) * 16;
    int offA[8], offB[4];
    #pragma unroll
    for (int m = 0; m < 8; ++m) offA[m] = (wr * 128 + m * 16 + fr) * 64 + x0;
    #pragma unroll
    for (int n = 0; n < 4; ++n) offB[n] = 16384 + (wc * 64 + n * 16 + fr) * 64 + x0;

    f32x4 acc[8][4] = {};
    const int nt = Kd >> 5;
    STAGE(0, 0);
    __syncthreads();
    for (int t = 0; t < nt; ++t) {
        if (t + 1 < nt) STAGE((t + 1) & 1, t + 1);
        const char* rb = lds2 + (t & 1) * 32768;
        bf16x8 a8[8], b4[4];
        #pragma unroll
        for (int m = 0; m < 8; ++m) a8[m] = *(const bf16x8*)(rb + offA[m]);
        #pragma unroll
        for (int n = 0; n < 4; ++n) b4[n] = *(const bf16x8*)(rb + offB[n]);
        #pragma unroll
        for (int m = 0; m < 8; ++m)
            #pragma unroll
            for (int n = 0; n < 4; ++n)
                acc[m][n] = __builtin_amdgcn_mfma_f32_16x16x32_bf16(a8[m], b4[n], acc[m][n], 0, 0, 0);
        __syncthreads();
    }

    const float* be = bias + e * Nd;
    ushort* Ce = C + (size_t)e * CAP * Nd;
    const int rl = (lane >> 4) * 4, cl = lane & 15;
    #pragma unroll
    for (int ni = 0; ni < 4; ++ni) {
        int gc = bn0 + wc * 64 + ni * 16 + cl;
        float bv = be[gc];
        #pragma unroll
        for (int mi = 0; mi < 8; ++mi) {
            #pragma unroll
            for (int r = 0; r < 4; ++r) {
                int gr = bm0 + wr * 128 + mi * 16 + rl + r;
                float v = acc[mi][ni][r] + bv;
                if (DOGELU) v = 0.5f * v * (1.f + erff(v * 0.70710678118654752f));
                Ce[(size_t)gr * Nd + gc] = f2bf(v);
            }
        }
    }
}

// ---------------- deterministic combine: out[t] = sum_k p_k * Y[dest_k] ----------------
__global__ void k_combine(const ushort* __restrict__ Y, const int* __restrict__ dest,
                          const float* __restrict__ probs, float* __restrict__ out) {
    int t = blockIdx.x;
    int h0 = threadIdx.x * 8;
    int d0 = dest[t * 2], d1 = dest[t * 2 + 1];
    float p0 = d0 >= 0 ? probs[t * 2] : 0.f;
    float p1 = d1 >= 0 ? probs[t * 2 + 1] : 0.f;
    int r0 = d0 >= 0 ? d0 : 0, r1 = d1 >= 0 ? d1 : 0;
    uint4 a = *(const uint4*)(Y + (size_t)r0 * HDIM + h0);
    uint4 b = *(const uint4*)(Y + (size_t)r1 * HDIM + h0);
    float4 o0, o1;
    o0.x = p0 * bf2f(a.x & 0xffff) + p1 * bf2f(b.x & 0xffff);
    o0.y = p0 * bf2f(a.x >> 16)    + p1 * bf2f(b.x >> 16);
    o0.z = p0 * bf2f(a.y & 0xffff) + p1 * bf2f(b.y & 0xffff);
    o0.w = p0 * bf2f(a.y >> 16)    + p1 * bf2f(b.y >> 16);
    o1.x = p0 * bf2f(a.z & 0xffff) + p1 * bf2f(b.z & 0xffff);
    o1.y = p0 * bf2f(a.z >> 16)    + p1 * bf2f(b.z >> 16);
    o1.z = p0 * bf2f(a.w & 0xffff) + p1 * bf2f(b.w & 0xffff);
    o1.w = p0 * bf2f(a.w >> 16)    + p1 * bf2f(b.w >> 16);
    float* op = out + (size_t)t * HDIM + h0;
    *(float4*)op = o0;
    *(float4*)(op + 4) = o1;
}

extern "C" void kernel_launch(void* const* d_in, const int* in_sizes, int n_in,
                              void* d_out, int out_size, void* d_ws, size_t ws_size,
                              hipStream_t stream) {
    const float* tokens = (const float*)d_in[0];
    const float* Wr     = (const float*)d_in[1];
    const float* br     = (const float*)d_in[2];
    const float* W1     = (const float*)d_in[3];
    const float* b1     = (const float*)d_in[4];
    const float* W2     = (const float*)d_in[5];
    const float* b2     = (const float*)d_in[6];
    float* out = (float*)d_out;
    char* ws = (char*)d_ws;

    int*    eids    = (int*)(ws);
    float*  probs   = (float*)(ws + 65536);
    int*    tok_map = (int*)(ws + 131072);
    int*    dest    = (int*)(ws + 172032);
    size_t off = 1u << 20;
    ushort* TbY = (ushort*)(ws + off);
    off += 41943040;
    ushort* Hm  = (ushort*)(ws + off);
    off += 83886080;
    ushort* WT  = (ushort*)(ws + off);
    (void)in_sizes; (void)n_in; (void)out_size; (void)ws_size;

    k_convert<<<dim3(NTOK * HDIM / 2048), 256, 0, stream>>>(tokens, TbY);
    k_router<<<dim3(NTOK / 4), 256, 0, stream>>>(tokens, Wr, br, eids, probs);
    k_assign<<<dim3(1), 64, 0, stream>>>(eids, tok_map, dest);
    k_transpose<<<dim3(HDIM / 64, FF / 64, NEXP), 256, 0, stream>>>(W1, WT, HDIM, FF);

    // --- ablation probes (junk writes to Hm; overwritten by real GEMM1 below) ---
    k_gemm<true, true, 1><<<dim3(FF / 256, CAP / 256, NEXP), 512, 0, stream>>>(
        TbY, tok_map, WT, b1, Hm, HDIM, FF);                       // p1: MFMA+barrier skeleton
    k_gemm<true, true, 2><<<dim3(FF / 256, CAP / 256, NEXP), 512, 0, stream>>>(
        TbY, tok_map, WT, b1, Hm, HDIM, FF);                       // p2: memory skeleton
    k_gemm_bk32<true, true><<<dim3(FF / 256, CAP / 256, NEXP), 512, 0, stream>>>(
        TbY, tok_map, WT, b1, Hm, HDIM, FF);                       // candidate: 2 blocks/CU

    // --- real pipeline ---
    k_gemm<true, true, 0><<<dim3(FF / 256, CAP / 256, NEXP), 512, 0, stream>>>(
        TbY, tok_map, WT, b1, Hm, HDIM, FF);
    k_transpose<<<dim3(FF / 64, HDIM / 64, NEXP), 256, 0, stream>>>(W2, WT, FF, HDIM);
    k_gemm<false, false, 0><<<dim3(HDIM / 256, CAP / 256, NEXP), 512, 0, stream>>>(
        Hm, nullptr, WT, b2, TbY, FF, HDIM);
    k_combine<<<dim3(NTOK), 256, 0, stream>>>(TbY, dest, probs, out);
}

// Round 6
// 1095.817 us; speedup vs baseline: 2.7068x; 2.7068x over previous
//
#include <hip/hip_runtime.h>
#include <hip/hip_bf16.h>
#include <math.h>

// Problem constants (reference: N=8192, H=2048, E=8, K=2, CF=1.25)
#define NTOK 8192
#define HDIM 2048
#define NEXP 8
#define TOPK 2
#define CAP  1280            // ceil(1.25 * 8192 / 8)
#define FF   4096            // 2*H

typedef float  f32x4  __attribute__((ext_vector_type(4)));
typedef __bf16 bf16x8 __attribute__((ext_vector_type(8)));

typedef __attribute__((address_space(1))) const unsigned int gas_u32;
typedef __attribute__((address_space(3))) unsigned int las_u32;

__device__ __forceinline__ void gload16(const void* g, void* l) {
    __builtin_amdgcn_global_load_lds((gas_u32*)g, (las_u32*)l, 16, 0, 0);
}

__device__ __forceinline__ ushort f2bf(float f) {
    union { float f; unsigned u; } c; c.f = f;
    unsigned u = c.u;
    unsigned r = (u + 0x7FFFu + ((u >> 16) & 1u)) >> 16;   // RNE
    return (ushort)r;
}
__device__ __forceinline__ float bf2f(ushort h) {
    union { unsigned u; float f; } c; c.u = ((unsigned)h) << 16;
    return c.f;
}

// ---------------- tokens f32 -> bf16 ----------------
__global__ void k_convert(const float* __restrict__ src, ushort* __restrict__ dst) {
    int i = (blockIdx.x * 256 + threadIdx.x) * 8;
    float4 a = *(const float4*)(src + i);
    float4 b = *(const float4*)(src + i + 4);
    uint4 o;
    o.x = (unsigned)f2bf(a.x) | ((unsigned)f2bf(a.y) << 16);
    o.y = (unsigned)f2bf(a.z) | ((unsigned)f2bf(a.w) << 16);
    o.z = (unsigned)f2bf(b.x) | ((unsigned)f2bf(b.y) << 16);
    o.w = (unsigned)f2bf(b.z) | ((unsigned)f2bf(b.w) << 16);
    *(uint4*)(dst + i) = o;
}

// ---------------- router: logits (f64 accum), top-2, softmax ----------------
__global__ void k_router(const float* __restrict__ tokens, const float* __restrict__ Wr,
                         const float* __restrict__ br, int* __restrict__ eids,
                         float* __restrict__ probs) {
    int wave = threadIdx.x >> 6, lane = threadIdx.x & 63;
    int t = blockIdx.x * 4 + wave;
    const float* tp = tokens + (size_t)t * HDIM;
    double acc[NEXP];
    #pragma unroll
    for (int e = 0; e < NEXP; ++e) acc[e] = 0.0;
    for (int j = 0; j < HDIM / 64; ++j) {
        float x = tp[j * 64 + lane];
        #pragma unroll
        for (int e = 0; e < NEXP; ++e)
            acc[e] += (double)x * (double)Wr[e * HDIM + j * 64 + lane];
    }
    #pragma unroll
    for (int e = 0; e < NEXP; ++e) {
        #pragma unroll
        for (int off = 32; off; off >>= 1) acc[e] += __shfl_xor(acc[e], off, 64);
    }
    if (lane == 0) {
        float lg[NEXP];
        #pragma unroll
        for (int e = 0; e < NEXP; ++e) lg[e] = (float)acc[e] + br[e];
        int e0 = 0; float s0 = lg[0];
        #pragma unroll
        for (int e = 1; e < NEXP; ++e) if (lg[e] > s0) { s0 = lg[e]; e0 = e; }
        int e1 = -1; float s1 = -1e30f;
        #pragma unroll
        for (int e = 0; e < NEXP; ++e) if (e != e0 && lg[e] > s1) { s1 = lg[e]; e1 = e; }
        float ex = expf(s1 - s0);
        float den = 1.f + ex;
        eids[t * 2] = e0; eids[t * 2 + 1] = e1;
        probs[t * 2] = 1.f / den; probs[t * 2 + 1] = ex / den;
    }
}

// ---------------- deterministic rank/capacity assignment (1 block, 1 wave) ----------------
__global__ void k_assign(const int* __restrict__ eids, int* __restrict__ tok_map,
                         int* __restrict__ dest) {
    __shared__ int cnt[64][NEXP];
    int l = threadIdx.x;
    for (int i = l; i < NEXP * CAP; i += 64) tok_map[i] = 0;
    int c[NEXP];
    #pragma unroll
    for (int e = 0; e < NEXP; ++e) c[e] = 0;
    const int base = l * 256;
    for (int i = 0; i < 256; ++i) {
        int ee = eids[base + i];
        #pragma unroll
        for (int e = 0; e < NEXP; ++e) c[e] += (ee == e);
    }
    #pragma unroll
    for (int e = 0; e < NEXP; ++e) cnt[l][e] = c[e];
    __syncthreads();
    if (l < NEXP) {
        int run = 0;
        for (int b = 0; b < 64; ++b) { int v = cnt[b][l]; cnt[b][l] = run; run += v; }
    }
    __syncthreads();
    int off[NEXP];
    #pragma unroll
    for (int e = 0; e < NEXP; ++e) off[e] = cnt[l][e];
    for (int i = 0; i < 256; ++i) {
        int d = base + i;
        int ee = eids[d];
        int r = -1;
        #pragma unroll
        for (int e = 0; e < NEXP; ++e) { bool m = (ee == e); if (m) r = off[e]; off[e] += m; }
        if (r < CAP) { tok_map[ee * CAP + r] = d >> 1; dest[d] = ee * CAP + r; }
        else dest[d] = -1;
    }
}

// ---------------- W [E][Kd][Nd] f32 -> WT [E][Nd][Kd] bf16, 64x64 tiles ----------------
__global__ __launch_bounds__(256) void k_transpose(const float* __restrict__ src,
                                                   ushort* __restrict__ dst,
                                                   int Kd, int Nd) {
    __shared__ float tl[64][65];
    int e = blockIdx.z;
    int k0 = blockIdx.x * 64, n0 = blockIdx.y * 64;
    const float* s = src + (size_t)e * Kd * Nd;
    ushort* d = dst + (size_t)e * Kd * Nd;
    int tid = threadIdx.x;
    #pragma unroll
    for (int i = 0; i < 4; ++i) {
        int flat = (i * 256 + tid) * 4;
        int kk = flat >> 6, nn = flat & 63;
        float4 v = *(const float4*)(s + (size_t)(k0 + kk) * Nd + n0 + nn);
        tl[kk][nn] = v.x; tl[kk][nn + 1] = v.y; tl[kk][nn + 2] = v.z; tl[kk][nn + 3] = v.w;
    }
    __syncthreads();
    #pragma unroll
    for (int g = 0; g < 4; ++g) {
        int flat = g * 1024 + tid * 4;
        int nn = flat >> 6, kk = flat & 63;
        uint2 o;
        o.x = (unsigned)f2bf(tl[kk][nn])     | ((unsigned)f2bf(tl[kk + 1][nn]) << 16);
        o.y = (unsigned)f2bf(tl[kk + 2][nn]) | ((unsigned)f2bf(tl[kk + 3][nn]) << 16);
        *(uint2*)(d + (size_t)(n0 + nn) * Kd + k0 + kk) = o;
    }
}

// ---------------- grouped bf16 MFMA GEMM, 256x256, 8-phase ONE-AHEAD pipeline ----------------
// C = act(A . B^T + bias). A: rows of Kd bf16 (via tmap if GATHER, else slot rows).
// B: [E][Nd][Kd] bf16 (K-contiguous). C: [E][CAP][Nd] bf16.
// 8 waves (2M x 4N), per-wave out 128x64. BK=64. LDS 128 KiB (A: buf*32K+half*16K; B: +64K).
// Derived-waits schedule: phase p issues ds_reads for quadrant Q_{p+1} into the alternate
// fragment bank, then BAR, then s_waitcnt lgkmcnt(N_issued_this_phase) -- FIFO-exact: drains
// precisely the reads Q_p consumes (issued last phase), leaving this phase's reads in flight.
// MFMA therefore starts at barrier release; LDS drain overlaps the MFMA pipe.
// vmcnt(4) at END of ph3/ph7 BEFORE the closing barrier (vmcnt is per-wave; the barrier is
// the cross-wave publish point for the buffer whose ds_reads are issued in the next phase).
// Outstanding-queue walk (steady state): vm queue holds 3 staged half-tiles (12 ops);
// vmcnt(4) confirms the 8 oldest = the buffer about to be read. lgkm: 12/4/8/0 per phase.
#define BAR()    __builtin_amdgcn_s_barrier()
#define SCHED0() __builtin_amdgcn_sched_barrier(0)
#define WAITL(n) do { asm volatile("s_waitcnt lgkmcnt(" #n ")" ::: "memory"); SCHED0(); } while (0)
#define VMC4()   do { asm volatile("s_waitcnt vmcnt(4)" ::: "memory"); SCHED0(); } while (0)

template<bool DOGELU, bool GATHER>
__global__ __launch_bounds__(512, 2) void k_gemm(const ushort* __restrict__ A,
                                                 const int* __restrict__ tmap,
                                                 const ushort* __restrict__ B,
                                                 const float* __restrict__ bias,
                                                 ushort* __restrict__ C,
                                                 int Kd, int Nd) {
    __shared__ char lds[131072];
    const int tid  = threadIdx.x;
    const int lane = tid & 63;
    const int wave = tid >> 6;
    const int wr = wave >> 2, wc = wave & 3;
    const int e = blockIdx.z;
    const int bm0 = blockIdx.y * 256, bn0 = blockIdx.x * 256;

    // ---------- staging setup (linear LDS dest + inverse-swizzled global source) ----------
    const int srow = tid >> 3;
    const int swzc = (tid ^ (tid >> 3)) & 7;
    const ushort* Be = B + (size_t)e * (size_t)Nd * Kd;
    const ushort* pa[4]; const ushort* pb[4];
    #pragma unroll
    for (int h = 0; h < 2; ++h)
        #pragma unroll
        for (int j = 0; j < 2; ++j) {
            int mrow = bm0 + h * 128 + j * 64 + srow;
            int arow = GATHER ? tmap[e * CAP + mrow] : (e * CAP + mrow);
            pa[h * 2 + j] = A  + (size_t)arow * Kd + swzc * 8;
            pb[h * 2 + j] = Be + (size_t)(bn0 + h * 128 + j * 64 + srow) * Kd + swzc * 8;
        }
    const int ldsW = wave * 1024;

    // ---------- compute-side fragment addressing (swizzled ds_read) ----------
    const int fr = lane & 15, kq = lane >> 4;
    const int x0 = ((kq ^ (fr & 7)) * 16);
    const int sA = wr * 16384 + fr * 128;
    const int sB = 65536 + (wc >> 1) * 16384 + ((wc & 1) * 64 + fr) * 128;

    f32x4  acc[8][4] = {};
    bf16x8 afA[4][2], afB[4][2];     // A-fragment banks (ping-pong by m-half)
    bf16x8 bfX[2][2], bfY[2][2];     // B-fragment banks (ping-pong by n-half)

    auto STAGE_A = [&](int b, int kt) {
        #pragma unroll
        for (int hj = 0; hj < 4; ++hj)
            gload16(pa[hj] + (size_t)kt * 64,
                    lds + b * 32768 + (hj >> 1) * 16384 + (hj & 1) * 8192 + ldsW);
    };
    auto STAGE_B = [&](int b, int kt) {
        #pragma unroll
        for (int hj = 0; hj < 4; ++hj)
            gload16(pb[hj] + (size_t)kt * 64,
                    lds + 65536 + b * 32768 + (hj >> 1) * 16384 + (hj & 1) * 8192 + ldsW);
    };
    auto LDAq = [&](bf16x8 (&bank)[4][2], int b, int mh) {    // 8 ds_read_b128
        #pragma unroll
        for (int m = 0; m < 4; ++m)
            #pragma unroll
            for (int ks = 0; ks < 2; ++ks)
                bank[m][ks] = *(const bf16x8*)(lds + b * 32768 + sA + (mh * 4 + m) * 2048
                                               + (x0 ^ (ks << 6)));
    };
    auto LDBq = [&](bf16x8 (&bank)[2][2], int b, int nh) {    // 4 ds_read_b128
        #pragma unroll
        for (int n = 0; n < 2; ++n)
            #pragma unroll
            for (int ks = 0; ks < 2; ++ks)
                bank[n][ks] = *(const bf16x8*)(lds + b * 32768 + sB + (nh * 2 + n) * 2048
                                               + (x0 ^ (ks << 6)));
    };
    auto MMAq = [&](bf16x8 (&A4)[4][2], bf16x8 (&B2)[2][2], int mh, int nh) {  // 16 MFMA
        __builtin_amdgcn_s_setprio(1);
        #pragma unroll
        for (int m = 0; m < 4; ++m)
            #pragma unroll
            for (int n = 0; n < 2; ++n)
                #pragma unroll
                for (int ks = 0; ks < 2; ++ks)
                    acc[mh * 4 + m][nh * 2 + n] = __builtin_amdgcn_mfma_f32_16x16x32_bf16(
                        A4[m][ks], B2[n][ks], acc[mh * 4 + m][nh * 2 + n], 0, 0, 0);
        __builtin_amdgcn_s_setprio(0);
        SCHED0();
    };

    const int NT  = Kd >> 6;       // K-tiles (32 or 64: even)
    const int nt2 = NT >> 1;

    // ---------- prologue ----------
    STAGE_A(0, 0); STAGE_B(0, 0); STAGE_B(1, 1);   // vm: 12 in flight
    VMC4();                                        // A(0),B(0) landed; B(1) in flight
    BAR();                                         // publish buf0
    LDAq(afA, 0, 0); LDBq(bfX, 0, 0);              // Q1 reads (12 lgkm in flight)

    for (int it = 0; it < nt2; ++it) {
        const int kt1  = 2 * it + 1;
        const int ktN  = min(2 * it + 2, NT - 1);
        const int ktN1 = min(2 * it + 3, NT - 1);
        // ph1: MFMA Q1(b0,m0,n0); issue Q2 reads; stage A(kt1)->buf1
        LDBq(bfY, 0, 1); STAGE_A(1, kt1);
        BAR(); WAITL(4);  MMAq(afA, bfX, 0, 0); BAR();
        // ph2: MFMA Q2(b0,m0,n1); issue Q3 reads
        LDAq(afB, 0, 1);
        BAR(); WAITL(8);  MMAq(afA, bfY, 0, 1); BAR();
        // ph3: MFMA Q3(b0,m1,n0); stage B(ktN)->buf0; vmcnt confirms buf1 before publish
        STAGE_B(0, ktN);
        BAR(); WAITL(0);  MMAq(afB, bfX, 1, 0); VMC4(); BAR();
        // ph4: MFMA Q4(b0,m1,n1); issue Q5 reads (buf1, now published)
        LDAq(afA, 1, 0); LDBq(bfX, 1, 0);
        BAR(); WAITL(12); MMAq(afB, bfY, 1, 1); BAR();
        // ph5: MFMA Q5(b1,m0,n0); issue Q6 reads; stage A(ktN)->buf0
        LDBq(bfY, 1, 1); STAGE_A(0, ktN);
        BAR(); WAITL(4);  MMAq(afA, bfX, 0, 0); BAR();
        // ph6: MFMA Q6(b1,m0,n1); issue Q7 reads
        LDAq(afB, 1, 1);
        BAR(); WAITL(8);  MMAq(afA, bfY, 0, 1); BAR();
        // ph7: MFMA Q7(b1,m1,n0); stage B(ktN1)->buf1; vmcnt confirms buf0-next before publish
        STAGE_B(1, ktN1);
        BAR(); WAITL(0);  MMAq(afB, bfX, 1, 0); VMC4(); BAR();
        // ph8: MFMA Q8(b1,m1,n1); issue next-iter Q1 reads (buf0)
        LDAq(afA, 0, 0); LDBq(bfX, 0, 0);
        BAR(); WAITL(12); MMAq(afB, bfY, 1, 1); BAR();
    }

    // ---------- epilogue ----------
    const float* be = bias + e * Nd;
    ushort* Ce = C + (size_t)e * CAP * Nd;
    const int rl = (lane >> 4) * 4, cl = lane & 15;
    #pragma unroll
    for (int ni = 0; ni < 4; ++ni) {
        int gc = bn0 + wc * 64 + ni * 16 + cl;
        float bv = be[gc];
        #pragma unroll
        for (int mi = 0; mi < 8; ++mi) {
            #pragma unroll
            for (int r = 0; r < 4; ++r) {
                int gr = bm0 + wr * 128 + mi * 16 + rl + r;
                float v = acc[mi][ni][r] + bv;
                if (DOGELU) v = 0.5f * v * (1.f + erff(v * 0.70710678118654752f));
                Ce[(size_t)gr * Nd + gc] = f2bf(v);
            }
        }
    }
}

// ---------------- deterministic combine: out[t] = sum_k p_k * Y[dest_k] ----------------
__global__ void k_combine(const ushort* __restrict__ Y, const int* __restrict__ dest,
                          const float* __restrict__ probs, float* __restrict__ out) {
    int t = blockIdx.x;
    int h0 = threadIdx.x * 8;
    int d0 = dest[t * 2], d1 = dest[t * 2 + 1];
    float p0 = d0 >= 0 ? probs[t * 2] : 0.f;
    float p1 = d1 >= 0 ? probs[t * 2 + 1] : 0.f;
    int r0 = d0 >= 0 ? d0 : 0, r1 = d1 >= 0 ? d1 : 0;
    uint4 a = *(const uint4*)(Y + (size_t)r0 * HDIM + h0);
    uint4 b = *(const uint4*)(Y + (size_t)r1 * HDIM + h0);
    float4 o0, o1;
    o0.x = p0 * bf2f(a.x & 0xffff) + p1 * bf2f(b.x & 0xffff);
    o0.y = p0 * bf2f(a.x >> 16)    + p1 * bf2f(b.x >> 16);
    o0.z = p0 * bf2f(a.y & 0xffff) + p1 * bf2f(b.y & 0xffff);
    o0.w = p0 * bf2f(a.y >> 16)    + p1 * bf2f(b.y >> 16);
    o1.x = p0 * bf2f(a.z & 0xffff) + p1 * bf2f(b.z & 0xffff);
    o1.y = p0 * bf2f(a.z >> 16)    + p1 * bf2f(b.z >> 16);
    o1.z = p0 * bf2f(a.w & 0xffff) + p1 * bf2f(b.w & 0xffff);
    o1.w = p0 * bf2f(a.w >> 16)    + p1 * bf2f(b.w >> 16);
    float* op = out + (size_t)t * HDIM + h0;
    *(float4*)op = o0;
    *(float4*)(op + 4) = o1;
}

extern "C" void kernel_launch(void* const* d_in, const int* in_sizes, int n_in,
                              void* d_out, int out_size, void* d_ws, size_t ws_size,
                              hipStream_t stream) {
    const float* tokens = (const float*)d_in[0];
    const float* Wr     = (const float*)d_in[1];
    const float* br     = (const float*)d_in[2];
    const float* W1     = (const float*)d_in[3];
    const float* b1     = (const float*)d_in[4];
    const float* W2     = (const float*)d_in[5];
    const float* b2     = (const float*)d_in[6];
    float* out = (float*)d_out;
    char* ws = (char*)d_ws;

    int*    eids    = (int*)(ws);
    float*  probs   = (float*)(ws + 65536);
    int*    tok_map = (int*)(ws + 131072);
    int*    dest    = (int*)(ws + 172032);
    size_t off = 1u << 20;
    ushort* TbY = (ushort*)(ws + off);
    off += 41943040;
    ushort* Hm  = (ushort*)(ws + off);
    off += 83886080;
    ushort* WT  = (ushort*)(ws + off);
    (void)in_sizes; (void)n_in; (void)out_size; (void)ws_size;

    k_convert<<<dim3(NTOK * HDIM / 2048), 256, 0, stream>>>(tokens, TbY);
    k_router<<<dim3(NTOK / 4), 256, 0, stream>>>(tokens, Wr, br, eids, probs);
    k_assign<<<dim3(1), 64, 0, stream>>>(eids, tok_map, dest);
    k_transpose<<<dim3(HDIM / 64, FF / 64, NEXP), 256, 0, stream>>>(W1, WT, HDIM, FF);
    k_gemm<true, true><<<dim3(FF / 256, CAP / 256, NEXP), 512, 0, stream>>>(
        TbY, tok_map, WT, b1, Hm, HDIM, FF);
    k_transpose<<<dim3(FF / 64, HDIM / 64, NEXP), 256, 0, stream>>>(W2, WT, FF, HDIM);
    k_gemm<false, false><<<dim3(HDIM / 256, CAP / 256, NEXP), 512, 0, stream>>>(
        Hm, nullptr, WT, b2, TbY, FF, HDIM);
    k_combine<<<dim3(NTOK), 256, 0, stream>>>(TbY, dest, probs, out);
}

// Round 7
// 751.430 us; speedup vs baseline: 3.9474x; 1.4583x over previous
//
#include <hip/hip_runtime.h>
#include <hip/hip_bf16.h>
#include <math.h>

// Problem constants (reference: N=8192, H=2048, E=8, K=2, CF=1.25)
#define NTOK 8192
#define HDIM 2048
#define NEXP 8
#define TOPK 2
#define CAP  1280            // ceil(1.25 * 8192 / 8)
#define FF   4096            // 2*H
#define BK   32              // GEMM K-step

typedef float  f32x4  __attribute__((ext_vector_type(4)));
typedef __bf16 bf16x8 __attribute__((ext_vector_type(8)));

typedef __attribute__((address_space(1))) const unsigned int gas_u32;
typedef __attribute__((address_space(3))) unsigned int las_u32;

__device__ __forceinline__ void gload16(const void* g, void* l) {
    // async global -> LDS, 16 B per lane; LDS dest = wave-uniform base + lane*16
    __builtin_amdgcn_global_load_lds((gas_u32*)g, (las_u32*)l, 16, 0, 0);
}

__device__ __forceinline__ ushort f2bf(float f) {
    union { float f; unsigned u; } c; c.f = f;
    unsigned u = c.u;
    unsigned r = (u + 0x7FFFu + ((u >> 16) & 1u)) >> 16;   // RNE
    return (ushort)r;
}
__device__ __forceinline__ float bf2f(ushort h) {
    union { unsigned u; float f; } c; c.u = ((unsigned)h) << 16;
    return c.f;
}

// ---------------- tokens f32 -> bf16 ----------------
__global__ void k_convert(const float* __restrict__ src, ushort* __restrict__ dst) {
    int i = (blockIdx.x * 256 + threadIdx.x) * 8;
    float4 a = *(const float4*)(src + i);
    float4 b = *(const float4*)(src + i + 4);
    uint4 o;
    o.x = (unsigned)f2bf(a.x) | ((unsigned)f2bf(a.y) << 16);
    o.y = (unsigned)f2bf(a.z) | ((unsigned)f2bf(a.w) << 16);
    o.z = (unsigned)f2bf(b.x) | ((unsigned)f2bf(b.y) << 16);
    o.w = (unsigned)f2bf(b.z) | ((unsigned)f2bf(b.w) << 16);
    *(uint4*)(dst + i) = o;
}

// ---------------- router: logits (f64 accum), top-2, softmax ----------------
__global__ void k_router(const float* __restrict__ tokens, const float* __restrict__ Wr,
                         const float* __restrict__ br, int* __restrict__ eids,
                         float* __restrict__ probs) {
    int wave = threadIdx.x >> 6, lane = threadIdx.x & 63;
    int t = blockIdx.x * 4 + wave;
    const float* tp = tokens + (size_t)t * HDIM;
    double acc[NEXP];
    #pragma unroll
    for (int e = 0; e < NEXP; ++e) acc[e] = 0.0;
    for (int j = 0; j < HDIM / 64; ++j) {
        float x = tp[j * 64 + lane];
        #pragma unroll
        for (int e = 0; e < NEXP; ++e)
            acc[e] += (double)x * (double)Wr[e * HDIM + j * 64 + lane];
    }
    #pragma unroll
    for (int e = 0; e < NEXP; ++e) {
        #pragma unroll
        for (int off = 32; off; off >>= 1) acc[e] += __shfl_xor(acc[e], off, 64);
    }
    if (lane == 0) {
        float lg[NEXP];
        #pragma unroll
        for (int e = 0; e < NEXP; ++e) lg[e] = (float)acc[e] + br[e];
        int e0 = 0; float s0 = lg[0];
        #pragma unroll
        for (int e = 1; e < NEXP; ++e) if (lg[e] > s0) { s0 = lg[e]; e0 = e; }
        int e1 = -1; float s1 = -1e30f;
        #pragma unroll
        for (int e = 0; e < NEXP; ++e) if (e != e0 && lg[e] > s1) { s1 = lg[e]; e1 = e; }
        float ex = expf(s1 - s0);
        float den = 1.f + ex;
        eids[t * 2] = e0; eids[t * 2 + 1] = e1;
        probs[t * 2] = 1.f / den; probs[t * 2 + 1] = ex / den;
    }
}

// ---------------- deterministic rank/capacity assignment (1 block, 1 wave) ----------------
__global__ void k_assign(const int* __restrict__ eids, int* __restrict__ tok_map,
                         int* __restrict__ dest) {
    __shared__ int cnt[64][NEXP];
    int l = threadIdx.x;
    for (int i = l; i < NEXP * CAP; i += 64) tok_map[i] = 0;
    int c[NEXP];
    #pragma unroll
    for (int e = 0; e < NEXP; ++e) c[e] = 0;
    const int base = l * 256;
    for (int i = 0; i < 256; ++i) {
        int ee = eids[base + i];
        #pragma unroll
        for (int e = 0; e < NEXP; ++e) c[e] += (ee == e);
    }
    #pragma unroll
    for (int e = 0; e < NEXP; ++e) cnt[l][e] = c[e];
    __syncthreads();
    if (l < NEXP) {
        int run = 0;
        for (int b = 0; b < 64; ++b) { int v = cnt[b][l]; cnt[b][l] = run; run += v; }
    }
    __syncthreads();
    int off[NEXP];
    #pragma unroll
    for (int e = 0; e < NEXP; ++e) off[e] = cnt[l][e];
    for (int i = 0; i < 256; ++i) {
        int d = base + i;
        int ee = eids[d];
        int r = -1;
        #pragma unroll
        for (int e = 0; e < NEXP; ++e) { bool m = (ee == e); if (m) r = off[e]; off[e] += m; }
        if (r < CAP) { tok_map[ee * CAP + r] = d >> 1; dest[d] = ee * CAP + r; }
        else dest[d] = -1;
    }
}

// ---------------- W [E][Kd][Nd] f32 -> WT [E][Nd][Kd] bf16, 64x64 tiles ----------------
__global__ __launch_bounds__(256) void k_transpose(const float* __restrict__ src,
                                                   ushort* __restrict__ dst,
                                                   int Kd, int Nd) {
    __shared__ float tl[64][65];
    int e = blockIdx.z;
    int k0 = blockIdx.x * 64, n0 = blockIdx.y * 64;
    const float* s = src + (size_t)e * Kd * Nd;
    ushort* d = dst + (size_t)e * Kd * Nd;
    int tid = threadIdx.x;
    #pragma unroll
    for (int i = 0; i < 4; ++i) {
        int flat = (i * 256 + tid) * 4;
        int kk = flat >> 6, nn = flat & 63;
        float4 v = *(const float4*)(s + (size_t)(k0 + kk) * Nd + n0 + nn);
        tl[kk][nn] = v.x; tl[kk][nn + 1] = v.y; tl[kk][nn + 2] = v.z; tl[kk][nn + 3] = v.w;
    }
    __syncthreads();
    #pragma unroll
    for (int g = 0; g < 4; ++g) {
        int flat = g * 1024 + tid * 4;
        int nn = flat >> 6, kk = flat & 63;
        uint2 o;
        o.x = (unsigned)f2bf(tl[kk][nn])     | ((unsigned)f2bf(tl[kk + 1][nn]) << 16);
        o.y = (unsigned)f2bf(tl[kk + 2][nn]) | ((unsigned)f2bf(tl[kk + 3][nn]) << 16);
        *(uint2*)(d + (size_t)(n0 + nn) * Kd + k0 + kk) = o;
    }
}

// ---------------- grouped bf16 MFMA GEMM: 128x128, BK=32, 3-buffer counted-vmcnt ----------------
// C = act(A . B^T + bias). A: rows of Kd bf16 (via tmap if GATHER, else slot rows).
// B: [E][Nd][Kd] bf16 (K-contiguous). C: [E][CAP][Nd] bf16.
// m97-class structure + T4: 3 LDS buffers (48 KiB), prefetch depth 2, vmcnt(4) (never 0),
// ONE barrier per iteration. Tail keeps vm-queue depth constant via dup-stage min(t+2,nt-1).
// Safety: all waves' reads of buf[t-1] complete (compiler lgkm wait precedes their MFMAs,
// which precede barrier t) before any post-barrier STAGE(t+2) overwrites buf[(t-1)%3].
// LDS swizzle (both-sides involution, conflict-free): 64 B rows, 4 chunks of 16 B;
// chunk position p at row r holds global k-chunk p ^ ((r>>2)&3); reads use the same XOR.
// XCD locality: 1-D grid, bid&7 = expert (blocks/expert == grid/8), so each XCD's
// default round-robin share is exactly one expert's panel.
#define SCHED0() __builtin_amdgcn_sched_barrier(0)
#define VMC4()   do { asm volatile("s_waitcnt vmcnt(4)" ::: "memory"); } while (0)

template<bool DOGELU, bool GATHER>
__global__ __launch_bounds__(256) void k_gemm(const ushort* __restrict__ A,
                                              const int* __restrict__ tmap,
                                              const ushort* __restrict__ B,
                                              const float* __restrict__ bias,
                                              ushort* __restrict__ C,
                                              int Kd, int Nd) {
    __shared__ __attribute__((aligned(128))) char lds[49152];   // 3 x (A 8K + B 8K)
    const int tid  = threadIdx.x;
    const int lane = tid & 63;
    const int wave = tid >> 6;
    const int wr = wave >> 1, wc = wave & 1;      // 2x2 wave grid, 64x64 out each
    // block decode: expert = bid&7 (grid = 8 * perE exactly); rem walks bx fastest
    const int NBX = Nd >> 7;
    const int nbxs = (NBX == 32) ? 5 : 4;
    const int bid = blockIdx.x;
    const int e = bid & 7;
    const int rem = bid >> 3;
    const int bm0 = (rem >> nbxs) * 128, bn0 = (rem & (NBX - 1)) * 128;

    const ushort* Be = B + (size_t)e * (size_t)Nd * Kd;
    // staging map: thread tid -> rows R, R+64 (R = tid>>2); LDS chunk p = tid&3;
    // global k-chunk g = p ^ ((R>>2)&3) = (tid&3) ^ ((tid>>4)&3)  [same for R and R+64]
    const int R  = tid >> 2;
    const int g  = (tid & 3) ^ ((tid >> 4) & 3);
    const int kc = g * 8;
    int ra0, ra1;
    if (GATHER) { ra0 = tmap[e * CAP + bm0 + R]; ra1 = tmap[e * CAP + bm0 + R + 64]; }
    else        { ra0 = e * CAP + bm0 + R;       ra1 = e * CAP + bm0 + R + 64; }
    const ushort* pa0 = A + (size_t)ra0 * Kd + kc;
    const ushort* pa1 = A + (size_t)ra1 * Kd + kc;
    const ushort* pb0 = Be + (size_t)(bn0 + R) * Kd + kc;
    const ushort* pb1 = Be + (size_t)(bn0 + R + 64) * Kd + kc;
    const int ldsW = wave * 1024;                 // wave-uniform lane block (1024 B / wave)

    auto STAGE = [&](int buf, int kt) {
        char* d = lds + buf * 16384;
        gload16(pa0 + kt * BK, d + ldsW);              // A rows 0-63
        gload16(pa1 + kt * BK, d + 4096 + ldsW);       // A rows 64-127
        gload16(pb0 + kt * BK, d + 8192 + ldsW);       // B rows 0-63
        gload16(pb1 + kt * BK, d + 12288 + ldsW);      // B rows 64-127
    };

    // compute-side fragment addressing (swizzled read: chunk = kq ^ ((fr>>2)&3))
    const int fr = lane & 15, kq = lane >> 4;
    const int cb = (kq ^ ((fr >> 2) & 3)) * 16;   // byte offset of 16B chunk within row
    int offA[4], offB[4];
    #pragma unroll
    for (int mi = 0; mi < 4; ++mi) offA[mi] = (wr * 64 + mi * 16 + fr) * 64 + cb;
    #pragma unroll
    for (int ni = 0; ni < 4; ++ni) offB[ni] = 8192 + (wc * 64 + ni * 16 + fr) * 64 + cb;

    f32x4 acc[4][4] = {};
    const int nt = Kd / BK;

    STAGE(0, 0); STAGE(1, 1);                      // vm queue: 8
    for (int t = 0; t < nt; ++t) {
        VMC4();                                    // oldest 4 = tile t landed (queue -> 4)
        __builtin_amdgcn_s_barrier();              // publish tile t; all t-1 reads done
        SCHED0();
        STAGE((t + 2) % 3, min(t + 2, nt - 1));    // refill queue to 8 (dup-stage at tail)
        const char* rb = lds + (t % 3) * 16384;
        bf16x8 af[4], bf[4];
        #pragma unroll
        for (int mi = 0; mi < 4; ++mi) af[mi] = *(const bf16x8*)(rb + offA[mi]);
        #pragma unroll
        for (int ni = 0; ni < 4; ++ni) bf[ni] = *(const bf16x8*)(rb + offB[ni]);
        #pragma unroll
        for (int mi = 0; mi < 4; ++mi)
            #pragma unroll
            for (int ni = 0; ni < 4; ++ni)
                acc[mi][ni] = __builtin_amdgcn_mfma_f32_16x16x32_bf16(af[mi], bf[ni],
                                                                      acc[mi][ni], 0, 0, 0);
    }

    const float* be = bias + e * Nd;
    ushort* Ce = C + (size_t)e * CAP * Nd;
    const int rl = (lane >> 4) * 4, cl = lane & 15;
    #pragma unroll
    for (int mi = 0; mi < 4; ++mi) {
        #pragma unroll
        for (int ni = 0; ni < 4; ++ni) {
            #pragma unroll
            for (int r = 0; r < 4; ++r) {
                int gr = bm0 + wr * 64 + mi * 16 + rl + r;
                int gc = bn0 + wc * 64 + ni * 16 + cl;
                float v = acc[mi][ni][r] + be[gc];
                if (DOGELU) v = 0.5f * v * (1.f + erff(v * 0.70710678118654752f));
                Ce[(size_t)gr * Nd + gc] = f2bf(v);
            }
        }
    }
}

// ---------------- deterministic combine: out[t] = sum_k p_k * Y[dest_k] ----------------
__global__ void k_combine(const ushort* __restrict__ Y, const int* __restrict__ dest,
                          const float* __restrict__ probs, float* __restrict__ out) {
    int t = blockIdx.x;
    int h0 = threadIdx.x * 8;
    int d0 = dest[t * 2], d1 = dest[t * 2 + 1];
    float p0 = d0 >= 0 ? probs[t * 2] : 0.f;
    float p1 = d1 >= 0 ? probs[t * 2 + 1] : 0.f;
    int r0 = d0 >= 0 ? d0 : 0, r1 = d1 >= 0 ? d1 : 0;
    uint4 a = *(const uint4*)(Y + (size_t)r0 * HDIM + h0);
    uint4 b = *(const uint4*)(Y + (size_t)r1 * HDIM + h0);
    float4 o0, o1;
    o0.x = p0 * bf2f(a.x & 0xffff) + p1 * bf2f(b.x & 0xffff);
    o0.y = p0 * bf2f(a.x >> 16)    + p1 * bf2f(b.x >> 16);
    o0.z = p0 * bf2f(a.y & 0xffff) + p1 * bf2f(b.y & 0xffff);
    o0.w = p0 * bf2f(a.y >> 16)    + p1 * bf2f(b.y >> 16);
    o1.x = p0 * bf2f(a.z & 0xffff) + p1 * bf2f(b.z & 0xffff);
    o1.y = p0 * bf2f(a.z >> 16)    + p1 * bf2f(b.z >> 16);
    o1.z = p0 * bf2f(a.w & 0xffff) + p1 * bf2f(b.w & 0xffff);
    o1.w = p0 * bf2f(a.w >> 16)    + p1 * bf2f(b.w >> 16);
    float* op = out + (size_t)t * HDIM + h0;
    *(float4*)op = o0;
    *(float4*)(op + 4) = o1;
}

extern "C" void kernel_launch(void* const* d_in, const int* in_sizes, int n_in,
                              void* d_out, int out_size, void* d_ws, size_t ws_size,
                              hipStream_t stream) {
    const float* tokens = (const float*)d_in[0];
    const float* Wr     = (const float*)d_in[1];
    const float* br     = (const float*)d_in[2];
    const float* W1     = (const float*)d_in[3];
    const float* b1     = (const float*)d_in[4];
    const float* W2     = (const float*)d_in[5];
    const float* b2     = (const float*)d_in[6];
    float* out = (float*)d_out;
    char* ws = (char*)d_ws;

    int*    eids    = (int*)(ws);
    float*  probs   = (float*)(ws + 65536);
    int*    tok_map = (int*)(ws + 131072);
    int*    dest    = (int*)(ws + 172032);
    size_t off = 1u << 20;
    ushort* TbY = (ushort*)(ws + off);             // tokens bf16 (33.5 MB) then Y bf16 (41.9 MB)
    off += 41943040;
    ushort* Hm  = (ushort*)(ws + off);             // gelu hidden bf16, 83.9 MB
    off += 83886080;
    ushort* WT  = (ushort*)(ws + off);             // W1T then W2T bf16, 134.2 MB
    (void)in_sizes; (void)n_in; (void)out_size; (void)ws_size;

    k_convert<<<dim3(NTOK * HDIM / 2048), 256, 0, stream>>>(tokens, TbY);
    k_router<<<dim3(NTOK / 4), 256, 0, stream>>>(tokens, Wr, br, eids, probs);
    k_assign<<<dim3(1), 64, 0, stream>>>(eids, tok_map, dest);
    k_transpose<<<dim3(HDIM / 64, FF / 64, NEXP), 256, 0, stream>>>(W1, WT, HDIM, FF);
    k_gemm<true, true><<<dim3((FF / 128) * (CAP / 128) * NEXP), 256, 0, stream>>>(
        TbY, tok_map, WT, b1, Hm, HDIM, FF);
    k_transpose<<<dim3(FF / 64, HDIM / 64, NEXP), 256, 0, stream>>>(W2, WT, FF, HDIM);
    k_gemm<false, false><<<dim3((HDIM / 128) * (CAP / 128) * NEXP), 256, 0, stream>>>(
        Hm, nullptr, WT, b2, TbY, FF, HDIM);
    k_combine<<<dim3(NTOK), 256, 0, stream>>>(TbY, dest, probs, out);
}

// Round 8
// 738.021 us; speedup vs baseline: 4.0191x; 1.0182x over previous
//
#include <hip/hip_runtime.h>
#include <hip/hip_bf16.h>
#include <math.h>

// Problem constants (reference: N=8192, H=2048, E=8, K=2, CF=1.25)
#define NTOK 8192
#define HDIM 2048
#define NEXP 8
#define TOPK 2
#define CAP  1280            // ceil(1.25 * 8192 / 8)
#define FF   4096            // 2*H
#define BK   32              // GEMM K-step

typedef float  f32x4  __attribute__((ext_vector_type(4)));
typedef __bf16 bf16x8 __attribute__((ext_vector_type(8)));

typedef __attribute__((address_space(1))) const unsigned int gas_u32;
typedef __attribute__((address_space(3))) unsigned int las_u32;

__device__ __forceinline__ void gload16(const void* g, void* l) {
    // async global -> LDS, 16 B per lane; LDS dest = wave-uniform base + lane*16
    __builtin_amdgcn_global_load_lds((gas_u32*)g, (las_u32*)l, 16, 0, 0);
}

__device__ __forceinline__ ushort f2bf(float f) {
    union { float f; unsigned u; } c; c.f = f;
    unsigned u = c.u;
    unsigned r = (u + 0x7FFFu + ((u >> 16) & 1u)) >> 16;   // RNE
    return (ushort)r;
}
__device__ __forceinline__ float bf2f(ushort h) {
    union { unsigned u; float f; } c; c.u = ((unsigned)h) << 16;
    return c.f;
}

// ---------------- tokens f32 -> bf16 ----------------
__global__ void k_convert(const float* __restrict__ src, ushort* __restrict__ dst) {
    int i = (blockIdx.x * 256 + threadIdx.x) * 8;
    float4 a = *(const float4*)(src + i);
    float4 b = *(const float4*)(src + i + 4);
    uint4 o;
    o.x = (unsigned)f2bf(a.x) | ((unsigned)f2bf(a.y) << 16);
    o.y = (unsigned)f2bf(a.z) | ((unsigned)f2bf(a.w) << 16);
    o.z = (unsigned)f2bf(b.x) | ((unsigned)f2bf(b.y) << 16);
    o.w = (unsigned)f2bf(b.z) | ((unsigned)f2bf(b.w) << 16);
    *(uint4*)(dst + i) = o;
}

// ---------------- router: logits (f64 accum), top-2, softmax ----------------
__global__ void k_router(const float* __restrict__ tokens, const float* __restrict__ Wr,
                         const float* __restrict__ br, int* __restrict__ eids,
                         float* __restrict__ probs) {
    int wave = threadIdx.x >> 6, lane = threadIdx.x & 63;
    int t = blockIdx.x * 4 + wave;
    const float* tp = tokens + (size_t)t * HDIM;
    double acc[NEXP];
    #pragma unroll
    for (int e = 0; e < NEXP; ++e) acc[e] = 0.0;
    for (int j = 0; j < HDIM / 64; ++j) {
        float x = tp[j * 64 + lane];
        #pragma unroll
        for (int e = 0; e < NEXP; ++e)
            acc[e] += (double)x * (double)Wr[e * HDIM + j * 64 + lane];
    }
    #pragma unroll
    for (int e = 0; e < NEXP; ++e) {
        #pragma unroll
        for (int off = 32; off; off >>= 1) acc[e] += __shfl_xor(acc[e], off, 64);
    }
    if (lane == 0) {
        float lg[NEXP];
        #pragma unroll
        for (int e = 0; e < NEXP; ++e) lg[e] = (float)acc[e] + br[e];
        int e0 = 0; float s0 = lg[0];
        #pragma unroll
        for (int e = 1; e < NEXP; ++e) if (lg[e] > s0) { s0 = lg[e]; e0 = e; }
        int e1 = -1; float s1 = -1e30f;
        #pragma unroll
        for (int e = 0; e < NEXP; ++e) if (e != e0 && lg[e] > s1) { s1 = lg[e]; e1 = e; }
        float ex = expf(s1 - s0);
        float den = 1.f + ex;
        eids[t * 2] = e0; eids[t * 2 + 1] = e1;
        probs[t * 2] = 1.f / den; probs[t * 2 + 1] = ex / den;
    }
}

// ---------------- deterministic rank/capacity assignment (1 block, 1 wave) ----------------
__global__ void k_assign(const int* __restrict__ eids, int* __restrict__ tok_map,
                         int* __restrict__ dest) {
    __shared__ int cnt[64][NEXP];
    int l = threadIdx.x;
    for (int i = l; i < NEXP * CAP; i += 64) tok_map[i] = 0;
    int c[NEXP];
    #pragma unroll
    for (int e = 0; e < NEXP; ++e) c[e] = 0;
    const int base = l * 256;
    for (int i = 0; i < 256; ++i) {
        int ee = eids[base + i];
        #pragma unroll
        for (int e = 0; e < NEXP; ++e) c[e] += (ee == e);
    }
    #pragma unroll
    for (int e = 0; e < NEXP; ++e) cnt[l][e] = c[e];
    __syncthreads();
    if (l < NEXP) {
        int run = 0;
        for (int b = 0; b < 64; ++b) { int v = cnt[b][l]; cnt[b][l] = run; run += v; }
    }
    __syncthreads();
    int off[NEXP];
    #pragma unroll
    for (int e = 0; e < NEXP; ++e) off[e] = cnt[l][e];
    for (int i = 0; i < 256; ++i) {
        int d = base + i;
        int ee = eids[d];
        int r = -1;
        #pragma unroll
        for (int e = 0; e < NEXP; ++e) { bool m = (ee == e); if (m) r = off[e]; off[e] += m; }
        if (r < CAP) { tok_map[ee * CAP + r] = d >> 1; dest[d] = ee * CAP + r; }
        else dest[d] = -1;
    }
}

// ---------------- W [E][Kd][Nd] f32 -> WT [E][Nd][Kd] bf16, 64x64 tiles ----------------
__global__ __launch_bounds__(256) void k_transpose(const float* __restrict__ src,
                                                   ushort* __restrict__ dst,
                                                   int Kd, int Nd) {
    __shared__ float tl[64][65];
    int e = blockIdx.z;
    int k0 = blockIdx.x * 64, n0 = blockIdx.y * 64;
    const float* s = src + (size_t)e * Kd * Nd;
    ushort* d = dst + (size_t)e * Kd * Nd;
    int tid = threadIdx.x;
    #pragma unroll
    for (int i = 0; i < 4; ++i) {
        int flat = (i * 256 + tid) * 4;
        int kk = flat >> 6, nn = flat & 63;
        float4 v = *(const float4*)(s + (size_t)(k0 + kk) * Nd + n0 + nn);
        tl[kk][nn] = v.x; tl[kk][nn + 1] = v.y; tl[kk][nn + 2] = v.z; tl[kk][nn + 3] = v.w;
    }
    __syncthreads();
    #pragma unroll
    for (int g = 0; g < 4; ++g) {
        int flat = g * 1024 + tid * 4;
        int nn = flat >> 6, kk = flat & 63;
        uint2 o;
        o.x = (unsigned)f2bf(tl[kk][nn])     | ((unsigned)f2bf(tl[kk + 1][nn]) << 16);
        o.y = (unsigned)f2bf(tl[kk + 2][nn]) | ((unsigned)f2bf(tl[kk + 3][nn]) << 16);
        *(uint2*)(d + (size_t)(n0 + nn) * Kd + k0 + kk) = o;
    }
}

// ---------------- grouped bf16 MFMA GEMM: 128x128, BK=32, 3-buffer counted-vmcnt ----------------
// C = act(A . B^T + bias). A: rows of Kd bf16 (via tmap if GATHER, else slot rows).
// B: [E][Nd][Kd] bf16 (K-contiguous). C: [E][CAP][Nd] bf16.
// m97-class structure + T4: 3 LDS buffers (48 KiB), prefetch depth 2, vmcnt(4) (never 0),
// ONE barrier per iteration. Tail keeps vm-queue depth constant via dup-stage min(t+2,nt-1).
// Safety: all waves' reads of buf[t-1] complete (compiler lgkm wait precedes their MFMAs,
// which precede barrier t) before any post-barrier STAGE(t+2) overwrites buf[(t-1)%3].
// LDS layout: linear [128 rows][32 k] per matrix (m97-faithful). The ~2.1e7 conflict
// cycles (~12%) are structural to 64-B rows (8 b128 bank-groups, 64 lanes) — accepted;
// round-7's chunk-XOR provably cannot fix it and measured as a no-op.
// Grid: 3-D (bx, by, e) — bx fastest => concurrent blocks of an expert spread across
// XCDs with only ~4 B-col-tiles (~2 MB) live per XCD L2 => B-panel L2-resident
// (round-2 evidence: FETCH 244 MB vs round-7's 1-D expert-per-XCD 589 MB thrash).
#define SCHED0() __builtin_amdgcn_sched_barrier(0)
#define VMC4()   do { asm volatile("s_waitcnt vmcnt(4)" ::: "memory"); } while (0)

template<bool DOGELU, bool GATHER>
__global__ __launch_bounds__(256) void k_gemm(const ushort* __restrict__ A,
                                              const int* __restrict__ tmap,
                                              const ushort* __restrict__ B,
                                              const float* __restrict__ bias,
                                              ushort* __restrict__ C,
                                              int Kd, int Nd) {
    __shared__ __attribute__((aligned(128))) char lds[49152];   // 3 x (A 8K + B 8K)
    const int tid  = threadIdx.x;
    const int lane = tid & 63;
    const int wave = tid >> 6;
    const int wr = wave >> 1, wc = wave & 1;      // 2x2 wave grid, 64x64 out each
    const int e = blockIdx.z;
    const int bm0 = blockIdx.y * 128, bn0 = blockIdx.x * 128;

    const ushort* Be = B + (size_t)e * (size_t)Nd * Kd;
    // staging map: thread tid -> rows R, R+64 (R = tid>>2); k-chunk kc = (tid&3)*8 elems.
    // LDS byte offset = R*64 + (tid&3)*16 = tid*16 (linear; wave base = wave*1024)
    const int R  = tid >> 2;
    const int kc = (tid & 3) * 8;
    int ra0, ra1;
    if (GATHER) { ra0 = tmap[e * CAP + bm0 + R]; ra1 = tmap[e * CAP + bm0 + R + 64]; }
    else        { ra0 = e * CAP + bm0 + R;       ra1 = e * CAP + bm0 + R + 64; }
    const ushort* pa0 = A + (size_t)ra0 * Kd + kc;
    const ushort* pa1 = A + (size_t)ra1 * Kd + kc;
    const ushort* pb0 = Be + (size_t)(bn0 + R) * Kd + kc;
    const ushort* pb1 = Be + (size_t)(bn0 + R + 64) * Kd + kc;
    const int ldsW = wave * 1024;                 // wave-uniform lane block (1024 B / wave)

    auto STAGE = [&](int buf, int kt) {
        char* d = lds + buf * 16384;
        gload16(pa0 + kt * BK, d + ldsW);              // A rows 0-63
        gload16(pa1 + kt * BK, d + 4096 + ldsW);       // A rows 64-127
        gload16(pb0 + kt * BK, d + 8192 + ldsW);       // B rows 0-63
        gload16(pb1 + kt * BK, d + 12288 + ldsW);      // B rows 64-127
    };

    // compute-side fragment addressing (linear: chunk = kq)
    const int fr = lane & 15, kq = lane >> 4;
    const int cb = kq * 16;                       // byte offset of 16B chunk within 64B row
    int offA[4], offB[4];
    #pragma unroll
    for (int mi = 0; mi < 4; ++mi) offA[mi] = (wr * 64 + mi * 16 + fr) * 64 + cb;
    #pragma unroll
    for (int ni = 0; ni < 4; ++ni) offB[ni] = 8192 + (wc * 64 + ni * 16 + fr) * 64 + cb;

    f32x4 acc[4][4] = {};
    const int nt = Kd / BK;

    STAGE(0, 0); STAGE(1, 1);                      // vm queue: 8
    for (int t = 0; t < nt; ++t) {
        VMC4();                                    // oldest 4 = tile t landed (queue -> 4)
        __builtin_amdgcn_s_barrier();              // publish tile t; all t-1 reads done
        SCHED0();
        STAGE((t + 2) % 3, min(t + 2, nt - 1));    // refill queue to 8 (dup-stage at tail)
        const char* rb = lds + (t % 3) * 16384;
        bf16x8 af[4], bf[4];
        #pragma unroll
        for (int mi = 0; mi < 4; ++mi) af[mi] = *(const bf16x8*)(rb + offA[mi]);
        #pragma unroll
        for (int ni = 0; ni < 4; ++ni) bf[ni] = *(const bf16x8*)(rb + offB[ni]);
        #pragma unroll
        for (int mi = 0; mi < 4; ++mi)
            #pragma unroll
            for (int ni = 0; ni < 4; ++ni)
                acc[mi][ni] = __builtin_amdgcn_mfma_f32_16x16x32_bf16(af[mi], bf[ni],
                                                                      acc[mi][ni], 0, 0, 0);
    }

    const float* be = bias + e * Nd;
    ushort* Ce = C + (size_t)e * CAP * Nd;
    const int rl = (lane >> 4) * 4, cl = lane & 15;
    #pragma unroll
    for (int mi = 0; mi < 4; ++mi) {
        #pragma unroll
        for (int ni = 0; ni < 4; ++ni) {
            #pragma unroll
            for (int r = 0; r < 4; ++r) {
                int gr = bm0 + wr * 64 + mi * 16 + rl + r;
                int gc = bn0 + wc * 64 + ni * 16 + cl;
                float v = acc[mi][ni][r] + be[gc];
                if (DOGELU) v = 0.5f * v * (1.f + erff(v * 0.70710678118654752f));
                Ce[(size_t)gr * Nd + gc] = f2bf(v);
            }
        }
    }
}

// ---------------- deterministic combine: out[t] = sum_k p_k * Y[dest_k] ----------------
__global__ void k_combine(const ushort* __restrict__ Y, const int* __restrict__ dest,
                          const float* __restrict__ probs, float* __restrict__ out) {
    int t = blockIdx.x;
    int h0 = threadIdx.x * 8;
    int d0 = dest[t * 2], d1 = dest[t * 2 + 1];
    float p0 = d0 >= 0 ? probs[t * 2] : 0.f;
    float p1 = d1 >= 0 ? probs[t * 2 + 1] : 0.f;
    int r0 = d0 >= 0 ? d0 : 0, r1 = d1 >= 0 ? d1 : 0;
    uint4 a = *(const uint4*)(Y + (size_t)r0 * HDIM + h0);
    uint4 b = *(const uint4*)(Y + (size_t)r1 * HDIM + h0);
    float4 o0, o1;
    o0.x = p0 * bf2f(a.x & 0xffff) + p1 * bf2f(b.x & 0xffff);
    o0.y = p0 * bf2f(a.x >> 16)    + p1 * bf2f(b.x >> 16);
    o0.z = p0 * bf2f(a.y & 0xffff) + p1 * bf2f(b.y & 0xffff);
    o0.w = p0 * bf2f(a.y >> 16)    + p1 * bf2f(b.y >> 16);
    o1.x = p0 * bf2f(a.z & 0xffff) + p1 * bf2f(b.z & 0xffff);
    o1.y = p0 * bf2f(a.z >> 16)    + p1 * bf2f(b.z >> 16);
    o1.z = p0 * bf2f(a.w & 0xffff) + p1 * bf2f(b.w & 0xffff);
    o1.w = p0 * bf2f(a.w >> 16)    + p1 * bf2f(b.w >> 16);
    float* op = out + (size_t)t * HDIM + h0;
    *(float4*)op = o0;
    *(float4*)(op + 4) = o1;
}

extern "C" void kernel_launch(void* const* d_in, const int* in_sizes, int n_in,
                              void* d_out, int out_size, void* d_ws, size_t ws_size,
                              hipStream_t stream) {
    const float* tokens = (const float*)d_in[0];
    const float* Wr     = (const float*)d_in[1];
    const float* br     = (const float*)d_in[2];
    const float* W1     = (const float*)d_in[3];
    const float* b1     = (const float*)d_in[4];
    const float* W2     = (const float*)d_in[5];
    const float* b2     = (const float*)d_in[6];
    float* out = (float*)d_out;
    char* ws = (char*)d_ws;

    int*    eids    = (int*)(ws);
    float*  probs   = (float*)(ws + 65536);
    int*    tok_map = (int*)(ws + 131072);
    int*    dest    = (int*)(ws + 172032);
    size_t off = 1u << 20;
    ushort* TbY = (ushort*)(ws + off);             // tokens bf16 (33.5 MB) then Y bf16 (41.9 MB)
    off += 41943040;
    ushort* Hm  = (ushort*)(ws + off);             // gelu hidden bf16, 83.9 MB
    off += 83886080;
    ushort* WT  = (ushort*)(ws + off);             // W1T then W2T bf16, 134.2 MB
    (void)in_sizes; (void)n_in; (void)out_size; (void)ws_size;

    k_convert<<<dim3(NTOK * HDIM / 2048), 256, 0, stream>>>(tokens, TbY);
    k_router<<<dim3(NTOK / 4), 256, 0, stream>>>(tokens, Wr, br, eids, probs);
    k_assign<<<dim3(1), 64, 0, stream>>>(eids, tok_map, dest);
    k_transpose<<<dim3(HDIM / 64, FF / 64, NEXP), 256, 0, stream>>>(W1, WT, HDIM, FF);
    k_gemm<true, true><<<dim3(FF / 128, CAP / 128, NEXP), 256, 0, stream>>>(
        TbY, tok_map, WT, b1, Hm, HDIM, FF);
    k_transpose<<<dim3(FF / 64, HDIM / 64, NEXP), 256, 0, stream>>>(W2, WT, FF, HDIM);
    k_gemm<false, false><<<dim3(HDIM / 128, CAP / 128, NEXP), 256, 0, stream>>>(
        Hm, nullptr, WT, b2, TbY, FF, HDIM);
    k_combine<<<dim3(NTOK), 256, 0, stream>>>(TbY, dest, probs, out);
}

// Round 9
// 732.005 us; speedup vs baseline: 4.0521x; 1.0082x over previous
//
#include <hip/hip_runtime.h>
#include <hip/hip_bf16.h>
#include <math.h>

// Problem constants (reference: N=8192, H=2048, E=8, K=2, CF=1.25)
#define NTOK 8192
#define HDIM 2048
#define NEXP 8
#define TOPK 2
#define CAP  1280            // ceil(1.25 * 8192 / 8)
#define FF   4096            // 2*H
#define BK   64              // GEMM K-step (128-B LDS rows -> G4 swizzle applies)

typedef float  f32x4  __attribute__((ext_vector_type(4)));
typedef __bf16 bf16x8 __attribute__((ext_vector_type(8)));

typedef __attribute__((address_space(1))) const unsigned int gas_u32;
typedef __attribute__((address_space(3))) unsigned int las_u32;

__device__ __forceinline__ void gload16(const void* g, void* l) {
    // async global -> LDS, 16 B per lane; LDS dest = wave-uniform base + lane*16
    __builtin_amdgcn_global_load_lds((gas_u32*)g, (las_u32*)l, 16, 0, 0);
}

__device__ __forceinline__ ushort f2bf(float f) {
    union { float f; unsigned u; } c; c.f = f;
    unsigned u = c.u;
    unsigned r = (u + 0x7FFFu + ((u >> 16) & 1u)) >> 16;   // RNE
    return (ushort)r;
}
__device__ __forceinline__ float bf2f(ushort h) {
    union { unsigned u; float f; } c; c.u = ((unsigned)h) << 16;
    return c.f;
}

// ---------------- tokens f32 -> bf16 ----------------
__global__ void k_convert(const float* __restrict__ src, ushort* __restrict__ dst) {
    int i = (blockIdx.x * 256 + threadIdx.x) * 8;
    float4 a = *(const float4*)(src + i);
    float4 b = *(const float4*)(src + i + 4);
    uint4 o;
    o.x = (unsigned)f2bf(a.x) | ((unsigned)f2bf(a.y) << 16);
    o.y = (unsigned)f2bf(a.z) | ((unsigned)f2bf(a.w) << 16);
    o.z = (unsigned)f2bf(b.x) | ((unsigned)f2bf(b.y) << 16);
    o.w = (unsigned)f2bf(b.z) | ((unsigned)f2bf(b.w) << 16);
    *(uint4*)(dst + i) = o;
}

// ---------------- router: logits (f64 accum), top-2, softmax ----------------
__global__ void k_router(const float* __restrict__ tokens, const float* __restrict__ Wr,
                         const float* __restrict__ br, int* __restrict__ eids,
                         float* __restrict__ probs) {
    int wave = threadIdx.x >> 6, lane = threadIdx.x & 63;
    int t = blockIdx.x * 4 + wave;
    const float* tp = tokens + (size_t)t * HDIM;
    double acc[NEXP];
    #pragma unroll
    for (int e = 0; e < NEXP; ++e) acc[e] = 0.0;
    for (int j = 0; j < HDIM / 64; ++j) {
        float x = tp[j * 64 + lane];
        #pragma unroll
        for (int e = 0; e < NEXP; ++e)
            acc[e] += (double)x * (double)Wr[e * HDIM + j * 64 + lane];
    }
    #pragma unroll
    for (int e = 0; e < NEXP; ++e) {
        #pragma unroll
        for (int off = 32; off; off >>= 1) acc[e] += __shfl_xor(acc[e], off, 64);
    }
    if (lane == 0) {
        float lg[NEXP];
        #pragma unroll
        for (int e = 0; e < NEXP; ++e) lg[e] = (float)acc[e] + br[e];
        int e0 = 0; float s0 = lg[0];
        #pragma unroll
        for (int e = 1; e < NEXP; ++e) if (lg[e] > s0) { s0 = lg[e]; e0 = e; }
        int e1 = -1; float s1 = -1e30f;
        #pragma unroll
        for (int e = 0; e < NEXP; ++e) if (e != e0 && lg[e] > s1) { s1 = lg[e]; e1 = e; }
        float ex = expf(s1 - s0);
        float den = 1.f + ex;
        eids[t * 2] = e0; eids[t * 2 + 1] = e1;
        probs[t * 2] = 1.f / den; probs[t * 2 + 1] = ex / den;
    }
}

// ---------------- deterministic rank/capacity assignment (1 block, 1 wave) ----------------
__global__ void k_assign(const int* __restrict__ eids, int* __restrict__ tok_map,
                         int* __restrict__ dest) {
    __shared__ int cnt[64][NEXP];
    int l = threadIdx.x;
    for (int i = l; i < NEXP * CAP; i += 64) tok_map[i] = 0;
    int c[NEXP];
    #pragma unroll
    for (int e = 0; e < NEXP; ++e) c[e] = 0;
    const int base = l * 256;
    for (int i = 0; i < 256; ++i) {
        int ee = eids[base + i];
        #pragma unroll
        for (int e = 0; e < NEXP; ++e) c[e] += (ee == e);
    }
    #pragma unroll
    for (int e = 0; e < NEXP; ++e) cnt[l][e] = c[e];
    __syncthreads();
    if (l < NEXP) {
        int run = 0;
        for (int b = 0; b < 64; ++b) { int v = cnt[b][l]; cnt[b][l] = run; run += v; }
    }
    __syncthreads();
    int off[NEXP];
    #pragma unroll
    for (int e = 0; e < NEXP; ++e) off[e] = cnt[l][e];
    for (int i = 0; i < 256; ++i) {
        int d = base + i;
        int ee = eids[d];
        int r = -1;
        #pragma unroll
        for (int e = 0; e < NEXP; ++e) { bool m = (ee == e); if (m) r = off[e]; off[e] += m; }
        if (r < CAP) { tok_map[ee * CAP + r] = d >> 1; dest[d] = ee * CAP + r; }
        else dest[d] = -1;
    }
}

// ---------------- W [E][Kd][Nd] f32 -> WT [E][Nd][Kd] bf16, 64x64 tiles ----------------
__global__ __launch_bounds__(256) void k_transpose(const float* __restrict__ src,
                                                   ushort* __restrict__ dst,
                                                   int Kd, int Nd) {
    __shared__ float tl[64][65];
    int e = blockIdx.z;
    int k0 = blockIdx.x * 64, n0 = blockIdx.y * 64;
    const float* s = src + (size_t)e * Kd * Nd;
    ushort* d = dst + (size_t)e * Kd * Nd;
    int tid = threadIdx.x;
    #pragma unroll
    for (int i = 0; i < 4; ++i) {
        int flat = (i * 256 + tid) * 4;
        int kk = flat >> 6, nn = flat & 63;
        float4 v = *(const float4*)(s + (size_t)(k0 + kk) * Nd + n0 + nn);
        tl[kk][nn] = v.x; tl[kk][nn + 1] = v.y; tl[kk][nn + 2] = v.z; tl[kk][nn + 3] = v.w;
    }
    __syncthreads();
    #pragma unroll
    for (int g = 0; g < 4; ++g) {
        int flat = g * 1024 + tid * 4;
        int nn = flat >> 6, kk = flat & 63;
        uint2 o;
        o.x = (unsigned)f2bf(tl[kk][nn])     | ((unsigned)f2bf(tl[kk + 1][nn]) << 16);
        o.y = (unsigned)f2bf(tl[kk + 2][nn]) | ((unsigned)f2bf(tl[kk + 3][nn]) << 16);
        *(uint2*)(d + (size_t)(n0 + nn) * Kd + k0 + kk) = o;
    }
}

// ---------------- grouped bf16 MFMA GEMM: 128x128, BK=64, 2-buffer stage-ahead ----------------
// C = act(A . B^T + bias). A: rows of Kd bf16 (via tmap if GATHER, else slot rows).
// B: [E][Nd][Kd] bf16 (K-contiguous). C: [E][CAP][Nd] bf16.
// T3-minimum 2-phase: barrier; STAGE(t+1 -> other buf); ds_reads+MFMA(t); vmcnt(0); barrier.
// Loads get the full compute phase (~1300 cyc) to land -> vmcnt(0) wait ~0 (m248 pattern).
// Buffer safety: STAGE(t+1) writes buf[(t+1)&1], read last at iter t-1; those reads
// completed before the barrier that opened iter t.
// LDS: 2 buffers x (A 16K + B 16K); 128-B rows, G4 XOR swizzle both-sides involution:
//   stage: position p = tid&7 holds global k-chunk p ^ (row&7)   (row = (tid>>3) + 32*round)
//   read:  chunk c = ks*4+kq at position c ^ (row&7)
// -> 64 lanes of each ds_read_b128 spread uniformly 8 lanes/16B-position = conflict-free
//    optimum (1 KB/instr at 128 B/cyc). Old 64-B layout was 16 lanes/position (2x, the
//    2.1e7 counter).
// Grid: 3-D (bx, by, e), bx fastest (round-8 locality, FETCH 310 MB).
#define SCHED0() __builtin_amdgcn_sched_barrier(0)
#define VMC0()   do { asm volatile("s_waitcnt vmcnt(0)" ::: "memory"); } while (0)

template<bool DOGELU, bool GATHER>
__global__ __launch_bounds__(256) void k_gemm(const ushort* __restrict__ A,
                                              const int* __restrict__ tmap,
                                              const ushort* __restrict__ B,
                                              const float* __restrict__ bias,
                                              ushort* __restrict__ C,
                                              int Kd, int Nd) {
    __shared__ __attribute__((aligned(128))) char lds[65536];   // 2 x (A 16K + B 16K)
    const int tid  = threadIdx.x;
    const int lane = tid & 63;
    const int wave = tid >> 6;
    const int wr = wave >> 1, wc = wave & 1;      // 2x2 wave grid, 64x64 out each
    const int e = blockIdx.z;
    const int bm0 = blockIdx.y * 128, bn0 = blockIdx.x * 128;

    const ushort* Be = B + (size_t)e * (size_t)Nd * Kd;
    // staging: round r (r=0..3) stages rows r*32 + (tid>>3); thread's chunk pos = tid&7;
    // source k-chunk = (tid&7) ^ (row&7) = (tid&7) ^ ((tid>>3)&7)  (round-invariant)
    const int rbase = tid >> 3;                   // 0..31
    const int kc = (((tid & 7) ^ (rbase & 7))) * 8;
    const ushort* pa[4]; const ushort* pb[4];
    #pragma unroll
    for (int r = 0; r < 4; ++r) {
        int gr = r * 32 + rbase;
        int arow = GATHER ? tmap[e * CAP + bm0 + gr] : (e * CAP + bm0 + gr);
        pa[r] = A  + (size_t)arow * Kd + kc;
        pb[r] = Be + (size_t)(bn0 + gr) * Kd + kc;
    }

    auto STAGE = [&](int buf, int kt) {
        char* d = lds + buf * 32768;
        #pragma unroll
        for (int r = 0; r < 4; ++r)
            gload16(pa[r] + kt * BK, d + r * 4096 + tid * 16);
        #pragma unroll
        for (int r = 0; r < 4; ++r)
            gload16(pb[r] + kt * BK, d + 16384 + r * 4096 + tid * 16);
    };

    // compute-side fragment addressing (swizzled read)
    const int fr = lane & 15, kq = lane >> 4;
    int offA[4][2], offB[4][2];
    #pragma unroll
    for (int m = 0; m < 4; ++m) {
        int row = wr * 64 + m * 16 + fr;
        #pragma unroll
        for (int ks = 0; ks < 2; ++ks)
            offA[m][ks] = row * 128 + (((ks * 4 + kq) ^ (row & 7)) * 16);
    }
    #pragma unroll
    for (int n = 0; n < 4; ++n) {
        int row = wc * 64 + n * 16 + fr;
        #pragma unroll
        for (int ks = 0; ks < 2; ++ks)
            offB[n][ks] = 16384 + row * 128 + (((ks * 4 + kq) ^ (row & 7)) * 16);
    }

    f32x4 acc[4][4] = {};
    const int nt = Kd / BK;

    STAGE(0, 0);
    VMC0();
    __builtin_amdgcn_s_barrier();
    for (int t = 0; t < nt; ++t) {
        if (t + 1 < nt) STAGE((t + 1) & 1, t + 1);
        SCHED0();
        const char* rb = lds + (t & 1) * 32768;
        bf16x8 af[4][2], bf[4][2];
        #pragma unroll
        for (int m = 0; m < 4; ++m)
            #pragma unroll
            for (int ks = 0; ks < 2; ++ks)
                af[m][ks] = *(const bf16x8*)(rb + offA[m][ks]);
        #pragma unroll
        for (int n = 0; n < 4; ++n)
            #pragma unroll
            for (int ks = 0; ks < 2; ++ks)
                bf[n][ks] = *(const bf16x8*)(rb + offB[n][ks]);
        #pragma unroll
        for (int ks = 0; ks < 2; ++ks)
            #pragma unroll
            for (int m = 0; m < 4; ++m)
                #pragma unroll
                for (int n = 0; n < 4; ++n)
                    acc[m][n] = __builtin_amdgcn_mfma_f32_16x16x32_bf16(af[m][ks], bf[n][ks],
                                                                        acc[m][n], 0, 0, 0);
        VMC0();                                    // tile t+1 landed (issued ~full phase ago)
        __builtin_amdgcn_s_barrier();              // publish buf[(t+1)&1]; reads of t done
    }

    const float* be = bias + e * Nd;
    ushort* Ce = C + (size_t)e * CAP * Nd;
    const int rl = (lane >> 4) * 4, cl = lane & 15;
    #pragma unroll
    for (int mi = 0; mi < 4; ++mi) {
        #pragma unroll
        for (int ni = 0; ni < 4; ++ni) {
            #pragma unroll
            for (int r = 0; r < 4; ++r) {
                int gr = bm0 + wr * 64 + mi * 16 + rl + r;
                int gc = bn0 + wc * 64 + ni * 16 + cl;
                float v = acc[mi][ni][r] + be[gc];
                if (DOGELU) v = 0.5f * v * (1.f + erff(v * 0.70710678118654752f));
                Ce[(size_t)gr * Nd + gc] = f2bf(v);
            }
        }
    }
}

// ---------------- deterministic combine: out[t] = sum_k p_k * Y[dest_k] ----------------
__global__ void k_combine(const ushort* __restrict__ Y, const int* __restrict__ dest,
                          const float* __restrict__ probs, float* __restrict__ out) {
    int t = blockIdx.x;
    int h0 = threadIdx.x * 8;
    int d0 = dest[t * 2], d1 = dest[t * 2 + 1];
    float p0 = d0 >= 0 ? probs[t * 2] : 0.f;
    float p1 = d1 >= 0 ? probs[t * 2 + 1] : 0.f;
    int r0 = d0 >= 0 ? d0 : 0, r1 = d1 >= 0 ? d1 : 0;
    uint4 a = *(const uint4*)(Y + (size_t)r0 * HDIM + h0);
    uint4 b = *(const uint4*)(Y + (size_t)r1 * HDIM + h0);
    float4 o0, o1;
    o0.x = p0 * bf2f(a.x & 0xffff) + p1 * bf2f(b.x & 0xffff);
    o0.y = p0 * bf2f(a.x >> 16)    + p1 * bf2f(b.x >> 16);
    o0.z = p0 * bf2f(a.y & 0xffff) + p1 * bf2f(b.y & 0xffff);
    o0.w = p0 * bf2f(a.y >> 16)    + p1 * bf2f(b.y >> 16);
    o1.x = p0 * bf2f(a.z & 0xffff) + p1 * bf2f(b.z & 0xffff);
    o1.y = p0 * bf2f(a.z >> 16)    + p1 * bf2f(b.z >> 16);
    o1.z = p0 * bf2f(a.w & 0xffff) + p1 * bf2f(b.w & 0xffff);
    o1.w = p0 * bf2f(a.w >> 16)    + p1 * bf2f(b.w >> 16);
    float* op = out + (size_t)t * HDIM + h0;
    *(float4*)op = o0;
    *(float4*)(op + 4) = o1;
}

extern "C" void kernel_launch(void* const* d_in, const int* in_sizes, int n_in,
                              void* d_out, int out_size, void* d_ws, size_t ws_size,
                              hipStream_t stream) {
    const float* tokens = (const float*)d_in[0];
    const float* Wr     = (const float*)d_in[1];
    const float* br     = (const float*)d_in[2];
    const float* W1     = (const float*)d_in[3];
    const float* b1     = (const float*)d_in[4];
    const float* W2     = (const float*)d_in[5];
    const float* b2     = (const float*)d_in[6];
    float* out = (float*)d_out;
    char* ws = (char*)d_ws;

    int*    eids    = (int*)(ws);
    float*  probs   = (float*)(ws + 65536);
    int*    tok_map = (int*)(ws + 131072);
    int*    dest    = (int*)(ws + 172032);
    size_t off = 1u << 20;
    ushort* TbY = (ushort*)(ws + off);             // tokens bf16 (33.5 MB) then Y bf16 (41.9 MB)
    off += 41943040;
    ushort* Hm  = (ushort*)(ws + off);             // gelu hidden bf16, 83.9 MB
    off += 83886080;
    ushort* WT  = (ushort*)(ws + off);             // W1T then W2T bf16, 134.2 MB
    (void)in_sizes; (void)n_in; (void)out_size; (void)ws_size;

    k_convert<<<dim3(NTOK * HDIM / 2048), 256, 0, stream>>>(tokens, TbY);
    k_router<<<dim3(NTOK / 4), 256, 0, stream>>>(tokens, Wr, br, eids, probs);
    k_assign<<<dim3(1), 64, 0, stream>>>(eids, tok_map, dest);
    k_transpose<<<dim3(HDIM / 64, FF / 64, NEXP), 256, 0, stream>>>(W1, WT, HDIM, FF);
    k_gemm<true, true><<<dim3(FF / 128, CAP / 128, NEXP), 256, 0, stream>>>(
        TbY, tok_map, WT, b1, Hm, HDIM, FF);
    k_transpose<<<dim3(FF / 64, HDIM / 64, NEXP), 256, 0, stream>>>(W2, WT, FF, HDIM);
    k_gemm<false, false><<<dim3(HDIM / 128, CAP / 128, NEXP), 256, 0, stream>>>(
        Hm, nullptr, WT, b2, TbY, FF, HDIM);
    k_combine<<<dim3(NTOK), 256, 0, stream>>>(TbY, dest, probs, out);
}